// Round 1
// baseline (490.179 us; speedup 1.0000x reference)
//
#include <hip/hip_runtime.h>

// MultiHeadAttention: B=4, T=2048, C=1024, H=16, HS=64
// out = softmax(causal((x@Wq)(x@Wk)^T * C^-0.5)) (x@Wv)  -> concat -> @Wproj + bproj

using u16    = unsigned short;
using bf16x8 = __attribute__((ext_vector_type(8))) short;  // 8 bf16 (4 VGPRs)
using f32x4  = __attribute__((ext_vector_type(4))) float;  // MFMA 16x16 C/D

#define MFMA_BF16(a, b, c) __builtin_amdgcn_mfma_f32_16x16x32_bf16((a), (b), (c), 0, 0, 0)

__device__ __forceinline__ u16 f2bf(float f) {
    union { float f; unsigned u; } v; v.f = f;
    unsigned u = v.u;
    u += 0x7FFFu + ((u >> 16) & 1u);   // RNE
    return (u16)(u >> 16);
}

// async global->LDS, 16B per lane; LDS dest must be wave-uniform base (+lane*16 by HW)
__device__ __forceinline__ void gl_lds16(const void* g, void* s) {
    __builtin_amdgcn_global_load_lds(
        (__attribute__((address_space(1))) void*)g,
        (__attribute__((address_space(3))) void*)s,
        16, 0, 0);
}

// ---------------- stage 1a: x fp32 -> bf16 ----------------
__global__ void cvt_x(const float* __restrict__ x, u16* __restrict__ xb, int n4) {
    int i = blockIdx.x * blockDim.x + threadIdx.x;
    if (i < n4) {
        float4 v = ((const float4*)x)[i];
        ushort4 o;
        o.x = f2bf(v.x); o.y = f2bf(v.y); o.z = f2bf(v.z); o.w = f2bf(v.w);
        ((ushort4*)xb)[i] = o;
    }
}

// ---------------- stage 1b: Wq/Wk/Wv [H][C][HS] fp32 -> WT[z][h*64+d][c] bf16 ----------------
__global__ void transpose_w(const float* __restrict__ Wq, const float* __restrict__ Wk,
                            const float* __restrict__ Wv, u16* __restrict__ WT) {
    __shared__ float tile[64][65];
    const int tid = threadIdx.x;
    const int c0  = blockIdx.x * 64;   // C-tile
    const int h   = blockIdx.y;
    const int z   = blockIdx.z;
    const float* W = (z == 0 ? Wq : (z == 1 ? Wk : Wv)) + (size_t)h * 1024 * 64;
    u16* out = WT + (size_t)z * 1024 * 1024 + (size_t)h * 64 * 1024;
    #pragma unroll
    for (int i = 0; i < 16; ++i) {
        int idx = i * 256 + tid;
        int r = idx >> 6, d = idx & 63;          // read W[c0+r][d], coalesced in d
        tile[d][r] = W[(size_t)(c0 + r) * 64 + d];
    }
    __syncthreads();
    #pragma unroll
    for (int i = 0; i < 16; ++i) {
        int idx = i * 256 + tid;
        int d = idx >> 6, j = idx & 63;          // write out[d][c0+j], coalesced in j
        out[(size_t)d * 1024 + c0 + j] = f2bf(tile[d][j]);
    }
}

// ---------------- stage 1c: Wproj [C][C] fp32 -> WpT[n][c] bf16 ----------------
__global__ void transpose_p(const float* __restrict__ Wp, u16* __restrict__ WpT) {
    __shared__ float tile[64][65];
    const int tid = threadIdx.x;
    const int c0  = blockIdx.x * 64;
    const int n0  = blockIdx.y * 64;
    #pragma unroll
    for (int i = 0; i < 16; ++i) {
        int idx = i * 256 + tid;
        int r = idx >> 6, j = idx & 63;          // Wp[c0+r][n0+j]
        tile[j][r] = Wp[(size_t)(c0 + r) * 1024 + n0 + j];
    }
    __syncthreads();
    #pragma unroll
    for (int i = 0; i < 16; ++i) {
        int idx = i * 256 + tid;
        int r = idx >> 6, j = idx & 63;          // WpT[n0+r][c0+j]
        WpT[(size_t)(n0 + r) * 1024 + c0 + j] = f2bf(tile[r][j]);
    }
}

// ---------------- m97-style bf16 GEMM: C[m][n] = A[m][k] * Bt[n][k]^T ----------------
// MODE 0: QKV projection (blockIdx.z selects Wq/Wk/Wv); Q scaled by 1/32;
//         Q,K -> [bh][t][64]; V -> [bh][64][t] (transposed for PV B-operand)
// MODE 1: output projection + bias -> fp32 out [8192][1024]
template <int MODE>
__global__ __launch_bounds__(256, 2)
void gemm_bt(const u16* __restrict__ A, const u16* __restrict__ Bt,
             u16* __restrict__ Oq, u16* __restrict__ Ok, u16* __restrict__ Ov,
             float* __restrict__ Op, const float* __restrict__ bias) {
    constexpr int K = 1024;
    __shared__ u16 As[128 * 32];
    __shared__ u16 Bs[128 * 32];
    const int tid  = threadIdx.x;
    const int w    = tid >> 6;
    const int lane = tid & 63;
    const int quad = lane >> 4;
    const int l16  = lane & 15;
    const int m0   = blockIdx.x * 128;
    const int n0   = blockIdx.y * 128;
    const u16* Bp  = (MODE == 0) ? (Bt + (size_t)blockIdx.z * 1024 * 1024) : Bt;

    const f32x4 zero = {0.f, 0.f, 0.f, 0.f};
    f32x4 acc[4][4];
    #pragma unroll
    for (int i = 0; i < 4; ++i)
        #pragma unroll
        for (int j = 0; j < 4; ++j) acc[i][j] = zero;

    const int wr = (w >> 1) * 64;
    const int wc = (w & 1) * 64;

    for (int k0 = 0; k0 < K; k0 += 32) {
        __syncthreads();
        #pragma unroll
        for (int i = 0; i < 2; ++i) {
            int c = i * 256 + tid;                 // chunk id, 512 x 16B = 8KB tile
            int row = c >> 2, ko = (c & 3) * 8;
            gl_lds16(A + (size_t)(m0 + row) * K + (k0 + ko), &As[(i * 256 + w * 64) * 8]);
        }
        #pragma unroll
        for (int i = 0; i < 2; ++i) {
            int c = i * 256 + tid;
            int row = c >> 2, ko = (c & 3) * 8;
            gl_lds16(Bp + (size_t)(n0 + row) * K + (k0 + ko), &Bs[(i * 256 + w * 64) * 8]);
        }
        __syncthreads();
        bf16x8 af[4], bfr[4];
        #pragma unroll
        for (int i = 0; i < 4; ++i)
            af[i] = *(const bf16x8*)&As[(wr + i * 16 + l16) * 32 + quad * 8];
        #pragma unroll
        for (int j = 0; j < 4; ++j)
            bfr[j] = *(const bf16x8*)&Bs[(wc + j * 16 + l16) * 32 + quad * 8];
        #pragma unroll
        for (int i = 0; i < 4; ++i)
            #pragma unroll
            for (int j = 0; j < 4; ++j)
                acc[i][j] = MFMA_BF16(af[i], bfr[j], acc[i][j]);
    }

    // epilogue: C/D layout row=(quad*4+r), col=l16 within each 16x16 frag (m89/m91-verified)
    #pragma unroll
    for (int i = 0; i < 4; ++i) {
        #pragma unroll
        for (int j = 0; j < 4; ++j) {
            #pragma unroll
            for (int r = 0; r < 4; ++r) {
                const int m = m0 + wr + i * 16 + quad * 4 + r;
                const int n = n0 + wc + j * 16 + l16;
                const float v = acc[i][j][r];
                if (MODE == 0) {
                    const int b = m >> 11, t = m & 2047;
                    const int h = n >> 6, d = n & 63;
                    const int bh = b * 16 + h;
                    if (blockIdx.z == 0)
                        Oq[((size_t)bh * 2048 + t) * 64 + d] = f2bf(v * 0.03125f);  // scale C^-0.5
                    else if (blockIdx.z == 1)
                        Ok[((size_t)bh * 2048 + t) * 64 + d] = f2bf(v);
                    else
                        Ov[((size_t)bh * 64 + d) * 2048 + t] = f2bf(v);             // V transposed
                } else {
                    Op[(size_t)m * 1024 + n] = v + bias[n];
                }
            }
        }
    }
}

// ---------------- flash attention: per (t-tile, b*h) block ----------------
// Q,K: [bh][T][64] bf16 (Q pre-scaled); Vt: [bh][64][T]; O -> Xo [b*T][1024] bf16 (head-concat)
__global__ __launch_bounds__(256, 2)
void attn(const u16* __restrict__ Q, const u16* __restrict__ Kk,
          const u16* __restrict__ Vt, u16* __restrict__ O) {
    __shared__ u16 Qs[64 * 64];
    __shared__ u16 Ks[64 * 64];
    __shared__ u16 Vs[64 * 64];       // [d][s]
    __shared__ u16 Ps[4][16 * 64];    // per-wave P in A-operand layout [t][s]
    const int tid  = threadIdx.x;
    const int w    = tid >> 6;
    const int lane = tid & 63;
    const int quad = lane >> 4;
    const int l16  = lane & 15;
    const int t0   = blockIdx.x * 64;
    const int bh   = blockIdx.y;
    const u16* Qp = Q  + (size_t)bh * 2048 * 64;
    const u16* Kp = Kk + (size_t)bh * 2048 * 64;
    const u16* Vp = Vt + (size_t)bh * 64 * 2048;

    // stage Q tile once: Qs[t][d]
    #pragma unroll
    for (int i = 0; i < 2; ++i) {
        int c = i * 256 + tid;
        int row = c >> 3, doff = (c & 7) * 8;
        gl_lds16(Qp + (size_t)(t0 + row) * 64 + doff, &Qs[(i * 256 + w * 64) * 8]);
    }

    const float NEG_INF = -__builtin_inff();
    const f32x4 zero = {0.f, 0.f, 0.f, 0.f};
    float mrow[4], lrow[4];
    f32x4 oacc[4];
    #pragma unroll
    for (int r = 0; r < 4; ++r) { mrow[r] = NEG_INF; lrow[r] = 0.f; }
    #pragma unroll
    for (int f = 0; f < 4; ++f) oacc[f] = zero;

    const int ns = blockIdx.x + 1;     // causal: s-tiles 0..t-tile
    for (int it = 0; it < ns; ++it) {
        const int s0 = it * 64;
        __syncthreads();               // prev iter LDS reads done (also drains Q staging)
        #pragma unroll
        for (int i = 0; i < 2; ++i) {  // K tile [s][d]
            int c = i * 256 + tid;
            int row = c >> 3, doff = (c & 7) * 8;
            gl_lds16(Kp + (size_t)(s0 + row) * 64 + doff, &Ks[(i * 256 + w * 64) * 8]);
        }
        #pragma unroll
        for (int i = 0; i < 2; ++i) {  // V tile [d][s]
            int c = i * 256 + tid;
            int drow = c >> 3, soff = (c & 7) * 8;
            gl_lds16(Vp + (size_t)drow * 2048 + (s0 + soff), &Vs[(i * 256 + w * 64) * 8]);
        }
        __syncthreads();               // staging complete

        // S = Q K^T for wave's 16 rows x 64 cols
        f32x4 sacc[4];
        #pragma unroll
        for (int j = 0; j < 4; ++j) sacc[j] = zero;
        #pragma unroll
        for (int kk = 0; kk < 64; kk += 32) {
            bf16x8 aq = *(const bf16x8*)&Qs[(w * 16 + l16) * 64 + kk + quad * 8];
            #pragma unroll
            for (int j = 0; j < 4; ++j) {
                bf16x8 bk = *(const bf16x8*)&Ks[(j * 16 + l16) * 64 + kk + quad * 8];
                sacc[j] = MFMA_BF16(aq, bk, sacc[j]);
            }
        }
        if (s0 == t0) {                // diagonal tile: mask s > t
            #pragma unroll
            for (int j = 0; j < 4; ++j)
                #pragma unroll
                for (int r = 0; r < 4; ++r) {
                    int t = t0 + w * 16 + quad * 4 + r;
                    int s = s0 + j * 16 + l16;
                    if (s > t) sacc[j][r] = NEG_INF;
                }
        }
        // online softmax; row stats replicated across the 16-lane quad group
        float alpha[4];
        #pragma unroll
        for (int r = 0; r < 4; ++r) {
            float mx = fmaxf(fmaxf(sacc[0][r], sacc[1][r]), fmaxf(sacc[2][r], sacc[3][r]));
            #pragma unroll
            for (int off = 1; off < 16; off <<= 1) mx = fmaxf(mx, __shfl_xor(mx, off, 16));
            float mnew = fmaxf(mrow[r], mx);
            alpha[r] = __expf(mrow[r] - mnew);
            mrow[r] = mnew;
            float rs = 0.f;
            #pragma unroll
            for (int j = 0; j < 4; ++j) {
                float p = __expf(sacc[j][r] - mnew);
                sacc[j][r] = p;
                rs += p;
            }
            #pragma unroll
            for (int off = 1; off < 16; off <<= 1) rs += __shfl_xor(rs, off, 16);
            lrow[r] = lrow[r] * alpha[r] + rs;
        }
        // P -> LDS (bf16, A-operand layout) and rescale O
        #pragma unroll
        for (int j = 0; j < 4; ++j)
            #pragma unroll
            for (int r = 0; r < 4; ++r)
                Ps[w][(quad * 4 + r) * 64 + j * 16 + l16] = f2bf(sacc[j][r]);
        #pragma unroll
        for (int f = 0; f < 4; ++f)
            #pragma unroll
            for (int r = 0; r < 4; ++r) oacc[f][r] *= alpha[r];
        __syncthreads();               // P visible (lgkm drained)

        // O += P V : A = P[t][s], B = Vs as [d][s] (B^T form)
        #pragma unroll
        for (int kk = 0; kk < 64; kk += 32) {
            bf16x8 ap = *(const bf16x8*)&Ps[w][l16 * 64 + kk + quad * 8];
            #pragma unroll
            for (int f = 0; f < 4; ++f) {
                bf16x8 bv = *(const bf16x8*)&Vs[(f * 16 + l16) * 64 + kk + quad * 8];
                oacc[f] = MFMA_BF16(ap, bv, oacc[f]);
            }
        }
    }
    // epilogue: O / l -> Xo[b*2048+t][h*64+d]
    const int b = bh >> 4, h = bh & 15;
    #pragma unroll
    for (int f = 0; f < 4; ++f)
        #pragma unroll
        for (int r = 0; r < 4; ++r) {
            int t = t0 + w * 16 + quad * 4 + r;
            int d = f * 16 + l16;
            float v = oacc[f][r] / lrow[r];
            O[((size_t)(b * 2048 + t)) * 1024 + h * 64 + d] = f2bf(v);
        }
}

extern "C" void kernel_launch(void* const* d_in, const int* in_sizes, int n_in,
                              void* d_out, int out_size, void* d_ws, size_t ws_size,
                              hipStream_t stream) {
    const float* x  = (const float*)d_in[0];
    const float* Wq = (const float*)d_in[1];
    const float* Wk = (const float*)d_in[2];
    const float* Wv = (const float*)d_in[3];
    const float* Wp = (const float*)d_in[4];
    const float* bp = (const float*)d_in[5];
    float* out = (float*)d_out;

    char* ws = (char*)d_ws;
    // layout (bytes): Xb/Xo share region 0 (Xb dead before attn writes Xo)
    u16* Xb  = (u16*)(ws);                          // [8192][1024] bf16 (16 MB)
    u16* Xo  = (u16*)(ws);                          // attn output, same region
    u16* WT  = (u16*)(ws + (16ull << 20));          // 3 x [1024][1024] (6 MB)
    u16* WpT = (u16*)(ws + (22ull << 20));          // [1024][1024] (2 MB)
    u16* Qw  = (u16*)(ws + (24ull << 20));          // [64][2048][64] (16 MB)
    u16* Kw  = (u16*)(ws + (40ull << 20));          // [64][2048][64] (16 MB)
    u16* Vw  = (u16*)(ws + (56ull << 20));          // [64][64][2048] (16 MB)
    // total 72 MB

    cvt_x<<<8192, 256, 0, stream>>>(x, Xb, 8192 * 1024 / 4);
    transpose_w<<<dim3(16, 16, 3), 256, 0, stream>>>(Wq, Wk, Wv, WT);
    transpose_p<<<dim3(16, 16), 256, 0, stream>>>(Wp, WpT);
    gemm_bt<0><<<dim3(64, 8, 3), 256, 0, stream>>>(Xb, WT, Qw, Kw, Vw, nullptr, nullptr);
    attn<<<dim3(32, 64), 256, 0, stream>>>(Qw, Kw, Vw, Xo);
    gemm_bt<1><<<dim3(64, 8, 1), 256, 0, stream>>>(Xo, WpT, nullptr, nullptr, nullptr, out, bp);
}